// Round 1
// baseline (798.205 us; speedup 1.0000x reference)
//
#include <hip/hip_runtime.h>
#include <hip/hip_bf16.h>
#include <stdint.h>

using f32x4  = __attribute__((ext_vector_type(4))) float;
using bf16x8 = __attribute__((ext_vector_type(8))) short;
using bf16x4 = __attribute__((ext_vector_type(4))) short;

#define NB   4
#define NC   128
#define NT   8192
#define TL   64
#define ROWB 272           // LDS row pitch bytes: 128 bf16 + 8 pad (=17*16B)
#define NLAYER 20

__device__ __forceinline__ short f2b(float f) {
  union { float f; unsigned u; } v; v.f = f;
  unsigned r = v.u + 0x7FFFu + ((v.u >> 16) & 1u);   // RNE
  return (short)(r >> 16);
}

__device__ __forceinline__ f32x4 mfma16(bf16x8 a, bf16x8 b, f32x4 c) {
  return __builtin_amdgcn_mfma_f32_16x16x32_bf16(a, b, c, 0, 0, 0);
}

// x [NB][NC][NT] f32 -> xt [NB][NT][NC] f32
__global__ void transpose_in(const float* __restrict__ x, float* __restrict__ xt) {
  __shared__ float tile[64][65];
  const int t0 = blockIdx.x * 64;
  const int c0 = blockIdx.y * 64;
  const int b  = blockIdx.z;
  const int lane = threadIdx.x & 63;
  const int r4   = threadIdx.x >> 6;   // 0..3
  #pragma unroll
  for (int i = 0; i < 16; ++i) {
    const int cl = i * 4 + r4;
    tile[cl][lane] = x[((size_t)(b * NC + c0 + cl)) * NT + t0 + lane];
  }
  __syncthreads();
  #pragma unroll
  for (int i = 0; i < 16; ++i) {
    const int tr = i * 4 + r4;
    xt[((size_t)(b * NT + t0 + tr)) * NC + c0 + lane] = tile[lane][tr];
  }
}

// One WaveNet layer. xin/xout: [NB][NT][NC] f32 (transposed activations).
// out: d_out base (x region [NB][NC][NT], then skips [NLAYER][NB][NC][NT]).
__global__ __launch_bounds__(512, 2)
void wavenet_layer(const float* __restrict__ w_conv,
                   const float* __restrict__ b_conv,
                   const float* __restrict__ w_out,
                   const float* __restrict__ b_out,
                   const float* __restrict__ xin,
                   float* __restrict__ xout,
                   float* __restrict__ out,
                   int layer, int dil, int last)
{
  __shared__ char lds[3 * TL * ROWB];
  char* ldsXP = lds;                    // x[t-d] tile, bf16 [TL][ROWB]
  char* ldsXC = lds + TL * ROWB;        // x[t]   tile
  char* ldsG  = lds + 2 * TL * ROWB;    // gated activations

  const int tid = threadIdx.x;
  const int w   = tid >> 6;        // wave 0..7
  const int l   = tid & 63;
  const int lh  = l & 15;
  const int lq  = l >> 4;          // 0..3
  const int t0  = blockIdx.x * TL;
  const int b   = blockIdx.y;

  // ---- stage X tiles (f32 -> bf16, already [t][c] layout) ----
  {
    const int srow = tid >> 3;     // 0..63
    const int j8   = tid & 7;      // 0..7
    const float* srcc = xin + ((size_t)(b * NT + t0 + srow)) * NC;
    #pragma unroll
    for (int q = 0; q < 4; ++q) {
      const int c4 = (j8 + 8 * q) * 4;
      f32x4 v = *(const f32x4*)(srcc + c4);
      bf16x4 bv;
      #pragma unroll
      for (int r = 0; r < 4; ++r) bv[r] = f2b(v[r]);
      *(bf16x4*)(ldsXC + srow * ROWB + c4 * 2) = bv;
    }
    const int tp = t0 + srow - dil;
    if (tp >= 0) {
      const float* srcp = xin + ((size_t)(b * NT + tp)) * NC;
      #pragma unroll
      for (int q = 0; q < 4; ++q) {
        const int c4 = (j8 + 8 * q) * 4;
        f32x4 v = *(const f32x4*)(srcp + c4);
        bf16x4 bv;
        #pragma unroll
        for (int r = 0; r < 4; ++r) bv[r] = f2b(v[r]);
        *(bf16x4*)(ldsXP + srow * ROWB + c4 * 2) = bv;
      }
    } else {
      bf16x4 zz; zz[0] = 0; zz[1] = 0; zz[2] = 0; zz[3] = 0;
      #pragma unroll
      for (int q = 0; q < 4; ++q)
        *(bf16x4*)(ldsXP + srow * ROWB + (j8 + 8 * q) * 8) = zz;
    }
  }

  // ---- preload conv-weight A fragments (bf16), k = tap*128 + c ----
  bf16x8 aw[2][8];
  #pragma unroll
  for (int mi = 0; mi < 2; ++mi) {
    const int o = mi * 128 + 16 * w + lh;
    #pragma unroll
    for (int ks = 0; ks < 8; ++ks) {
      const int kb  = ks * 32 + lq * 8;
      const int tap = kb >> 7;
      const int c   = kb & 127;
      const float* p = w_conv + ((((size_t)layer * 256 + o) * 128 + c) * 2 + tap);
      bf16x8 a;
      #pragma unroll
      for (int j = 0; j < 8; ++j) a[j] = f2b(p[2 * j]);
      aw[mi][ks] = a;
    }
  }

  __syncthreads();

  // ---- GEMM1: z[256 x TL] ----
  f32x4 acc1[2][4];
  #pragma unroll
  for (int mi = 0; mi < 2; ++mi)
    #pragma unroll
    for (int n = 0; n < 4; ++n) {
      acc1[mi][n][0] = 0.f; acc1[mi][n][1] = 0.f;
      acc1[mi][n][2] = 0.f; acc1[mi][n][3] = 0.f;
    }
  #pragma unroll
  for (int ks = 0; ks < 8; ++ks) {
    const char* base = (ks < 4) ? ldsXP : ldsXC;
    const int c = (ks * 32 + lq * 8) & 127;
    #pragma unroll
    for (int n = 0; n < 4; ++n) {
      const int tt = n * 16 + lh;
      bf16x8 bb = *(const bf16x8*)(base + tt * ROWB + c * 2);
      acc1[0][n] = mfma16(aw[0][ks], bb, acc1[0][n]);
      acc1[1][n] = mfma16(aw[1][ks], bb, acc1[1][n]);
    }
  }

  // ---- gate: g = tanh(z_a) * sigmoid(z_b), write bf16 to ldsG ----
  {
    float ba[4], bs[4];
    #pragma unroll
    for (int r = 0; r < 4; ++r) {
      ba[r] = b_conv[layer * 256 + 16 * w + lq * 4 + r];
      bs[r] = b_conv[layer * 256 + 128 + 16 * w + lq * 4 + r];
    }
    const int c0 = 16 * w + lq * 4;
    #pragma unroll
    for (int n = 0; n < 4; ++n) {
      bf16x4 g4;
      #pragma unroll
      for (int r = 0; r < 4; ++r) {
        const float za = acc1[0][n][r] + ba[r];
        const float zb = acc1[1][n][r] + bs[r];
        const float th = 1.f - 2.f / (1.f + __expf(2.f * za));
        const float sg = 1.f / (1.f + __expf(-zb));
        g4[r] = f2b(th * sg);
      }
      const int tt = n * 16 + lh;
      *(bf16x4*)(ldsG + tt * ROWB + c0 * 2) = g4;
    }
  }

  // ---- preload Wout A fragments ----
  bf16x8 awo[4];
  {
    const int o = 16 * w + lh;
    #pragma unroll
    for (int ks = 0; ks < 4; ++ks) {
      const float* p = w_out + ((size_t)layer * 128 + o) * 128 + ks * 32 + lq * 8;
      bf16x8 a;
      #pragma unroll
      for (int j = 0; j < 8; ++j) a[j] = f2b(p[j]);
      awo[ks] = a;
    }
  }

  __syncthreads();

  // ---- GEMM2: s[128 x TL] = Wout * G ----
  f32x4 acc2[4];
  #pragma unroll
  for (int n = 0; n < 4; ++n) {
    acc2[n][0] = 0.f; acc2[n][1] = 0.f; acc2[n][2] = 0.f; acc2[n][3] = 0.f;
  }
  #pragma unroll
  for (int ks = 0; ks < 4; ++ks) {
    const int c = ks * 32 + lq * 8;
    #pragma unroll
    for (int n = 0; n < 4; ++n) {
      const int tt = n * 16 + lh;
      bf16x8 bb = *(const bf16x8*)(ldsG + tt * ROWB + c * 2);
      acc2[n] = mfma16(awo[ks], bb, acc2[n]);
    }
  }

  // ---- epilogue: skips, residual (f32 chain via xin/xout), final x ----
  {
    const size_t XOFFS = (size_t)NB * NC * NT;
    float bo[4];
    #pragma unroll
    for (int r = 0; r < 4; ++r) bo[r] = b_out[layer * 128 + 16 * w + lq * 4 + r];
    #pragma unroll
    for (int n = 0; n < 4; ++n) {
      const int tg = t0 + n * 16 + lh;
      #pragma unroll
      for (int r = 0; r < 4; ++r) {
        const int o = 16 * w + lq * 4 + r;
        const float s = acc2[n][r] + bo[r];
        out[XOFFS + ((size_t)((layer * NB + b) * NC + o)) * NT + tg] = s;
        const size_t xi = ((size_t)(b * NT + tg)) * NC + o;
        const float xn = s + xin[xi];
        xout[xi] = xn;
        if (last) out[((size_t)(b * NC + o)) * NT + tg] = xn;
      }
    }
  }
}

extern "C" void kernel_launch(void* const* d_in, const int* in_sizes, int n_in,
                              void* d_out, int out_size, void* d_ws, size_t ws_size,
                              hipStream_t stream) {
  const float* x      = (const float*)d_in[0];
  const float* w_conv = (const float*)d_in[1];
  const float* b_conv = (const float*)d_in[2];
  const float* w_out  = (const float*)d_in[3];
  const float* b_out  = (const float*)d_in[4];
  float* out = (float*)d_out;

  const size_t XTN = (size_t)NB * NT * NC;  // 4,194,304 floats = 16 MB
  float* xt_a = (float*)d_ws;
  float* xt_b = xt_a + XTN;

  transpose_in<<<dim3(NT / 64, NC / 64, NB), 256, 0, stream>>>(x, xt_a);

  static const int dil[NLAYER] = {1, 2, 4, 8, 16, 32, 64, 128, 256, 512,
                                  1, 2, 4, 8, 16, 32, 64, 128, 256, 512};
  for (int i = 0; i < NLAYER; ++i) {
    const float* xi = (i & 1) ? xt_b : xt_a;
    float*       xo = (i & 1) ? xt_a : xt_b;
    wavenet_layer<<<dim3(NT / TL, NB), 512, 0, stream>>>(
        w_conv, b_conv, w_out, b_out, xi, xo, out, i, dil[i],
        (i == NLAYER - 1) ? 1 : 0);
  }
}

// Round 3
// 458.138 us; speedup vs baseline: 1.7423x; 1.7423x over previous
//
#include <hip/hip_runtime.h>
#include <hip/hip_bf16.h>
#include <stdint.h>

using f32x4  = __attribute__((ext_vector_type(4))) float;
using bf16x8 = __attribute__((ext_vector_type(8))) short;
using bf16x4 = __attribute__((ext_vector_type(4))) short;

#define NB   4
#define NC   128
#define NT   8192
#define TL   64
#define NLAYER 20
#define GROWB 272          // padded LDS pitch for G tile
#define CONVN (NLAYER * 256 * 256)
#define WOUTN (NLAYER * 128 * 128)

__device__ __forceinline__ short f2b(float f) {
  union { float f; unsigned u; } v; v.f = f;
  unsigned r = v.u + 0x7FFFu + ((v.u >> 16) & 1u);   // RNE
  return (short)(r >> 16);
}

__device__ __forceinline__ f32x4 mfma16(bf16x8 a, bf16x8 b, f32x4 c) {
  return __builtin_amdgcn_mfma_f32_16x16x32_bf16(a, b, c, 0, 0, 0);
}

__device__ __forceinline__ void gl_lds16(const void* g, void* l) {
  __builtin_amdgcn_global_load_lds(
      (const __attribute__((address_space(1))) void*)g,
      (__attribute__((address_space(3))) void*)l, 16, 0, 0);
}

// x [NB][NC][NT] f32 -> xt [NB][NT][NC] f32  +  xtb bf16 swizzled (256B rows)
__global__ void transpose_in(const float* __restrict__ x, float* __restrict__ xt,
                             short* __restrict__ xtb) {
  __shared__ float tile[64][65];
  const int t0 = blockIdx.x * 64;
  const int c0 = blockIdx.y * 64;
  const int b  = blockIdx.z;
  const int lane = threadIdx.x & 63;
  const int r4   = threadIdx.x >> 6;   // 0..3
  #pragma unroll
  for (int i = 0; i < 16; ++i) {
    const int cl = i * 4 + r4;
    tile[cl][lane] = x[((size_t)(b * NC + c0 + cl)) * NT + t0 + lane];
  }
  __syncthreads();
  #pragma unroll
  for (int i = 0; i < 16; ++i) {
    const int tr = i * 4 + r4;
    const float v = tile[lane][tr];
    const int t = t0 + tr, c = c0 + lane;
    xt[((size_t)(b * NT + t)) * NC + c] = v;
    const size_t rowB = ((size_t)(b * NT + t)) * 256;
    const int ci = (c >> 3) ^ (t & 7);
    *(short*)((char*)xtb + rowB + ci * 16 + (c & 7) * 2) = f2b(v);
  }
}

// pack weights to bf16, fragment-ordered: wcb[l][o][k] with k = tap*128 + c
__global__ void pack_weights(const float* __restrict__ w_conv,
                             const float* __restrict__ w_out,
                             short* __restrict__ wcb, short* __restrict__ wob) {
  const int idx = blockIdx.x * 256 + threadIdx.x;
  if (idx < CONVN) {
    const int k = idx & 255, o = (idx >> 8) & 255, lyr = idx >> 16;
    const int tap = k >> 7, c = k & 127;
    wcb[idx] = f2b(w_conv[(((size_t)lyr * 256 + o) * 128 + c) * 2 + tap]);
  } else if (idx < CONVN + WOUTN) {
    const int j = idx - CONVN;
    wob[j] = f2b(w_out[j]);
  }
}

__global__ __launch_bounds__(512, 4)
void wavenet_layer(const short* __restrict__ wcb,
                   const float* __restrict__ b_conv,
                   const short* __restrict__ wob,
                   const float* __restrict__ b_out,
                   const float* __restrict__ xin,   // f32 [b][t][c]
                   const short* __restrict__ xbin,  // bf16 swizzled [b][t] 256B rows
                   float* __restrict__ xout,
                   short* __restrict__ xbout,
                   float* __restrict__ out,
                   int layer, int dil, int last)
{
  __shared__ char ldsXP[TL * 256];
  __shared__ char ldsXC[TL * 256];
  __shared__ char ldsG[TL * GROWB];

  const int tid = threadIdx.x;
  const int w   = tid >> 6;
  const int l   = tid & 63;
  const int lh  = l & 15;
  const int lq  = l >> 4;
  const int t0  = blockIdx.x * TL;
  const int b   = blockIdx.y;

  // ---- stage XC tile (always valid) via global_load_lds ----
  {
    const char* xcg = (const char*)xbin + ((size_t)(b * NT + t0)) * 256;
    const int off = w * 2048 + l * 16;
    gl_lds16(xcg + off, ldsXC + off);
    gl_lds16(xcg + off + 1024, ldsXC + off + 1024);
  }
  // ---- stage XP tile ----
  if (t0 >= dil) {
    const char* xpg = (const char*)xbin + ((size_t)(b * NT + t0 - dil)) * 256;
    const int off = w * 2048 + l * 16;
    gl_lds16(xpg + off, ldsXP + off);
    gl_lds16(xpg + off + 1024, ldsXP + off + 1024);
  } else {
    const int row = tid >> 3, j8 = tid & 7;
    const int tp = t0 + row - dil;
    char* dst = ldsXP + row * 256;
    if (tp >= 0) {
      const char* src = (const char*)xbin + ((size_t)(b * NT + tp)) * 256;
      *(bf16x8*)(dst + j8 * 16)       = *(const bf16x8*)(src + j8 * 16);
      *(bf16x8*)(dst + j8 * 16 + 128) = *(const bf16x8*)(src + j8 * 16 + 128);
    } else {
      bf16x8 z = {0, 0, 0, 0, 0, 0, 0, 0};
      *(bf16x8*)(dst + j8 * 16)       = z;
      *(bf16x8*)(dst + j8 * 16 + 128) = z;
    }
  }
  __syncthreads();

  // ---- GEMM1: z[256 x TL], k = tap*128 + c; tap0 -> XP, tap1 -> XC ----
  const f32x4 fz = {0.f, 0.f, 0.f, 0.f};
  f32x4 acc1[2][4];
  #pragma unroll
  for (int mi = 0; mi < 2; ++mi)
    #pragma unroll
    for (int n = 0; n < 4; ++n) acc1[mi][n] = fz;

  const short* wl = wcb + (size_t)layer * 256 * 256;
  #pragma unroll
  for (int ks = 0; ks < 8; ++ks) {
    const bf16x8 a0 = *(const bf16x8*)(wl + (16 * w + lh) * 256 + ks * 32 + lq * 8);
    const bf16x8 a1 = *(const bf16x8*)(wl + (128 + 16 * w + lh) * 256 + ks * 32 + lq * 8);
    const char* base = (ks < 4) ? ldsXP : ldsXC;
    const int dd = (ks < 4) ? dil : 0;
    #pragma unroll
    for (int n = 0; n < 4; ++n) {
      const int tt = n * 16 + lh;
      const int ci = ((ks & 3) * 4 + lq) ^ ((tt - dd) & 7);   // FIX: wrap channel group
      const bf16x8 bb = *(const bf16x8*)(base + tt * 256 + ci * 16);
      acc1[0][n] = mfma16(a0, bb, acc1[0][n]);
      acc1[1][n] = mfma16(a1, bb, acc1[1][n]);
    }
  }

  // ---- gate: g = tanh(z_a) * sigmoid(z_b) -> bf16 ldsG ----
  {
    float ba[4], bs[4];
    #pragma unroll
    for (int r = 0; r < 4; ++r) {
      ba[r] = b_conv[layer * 256 + 16 * w + lq * 4 + r];
      bs[r] = b_conv[layer * 256 + 128 + 16 * w + lq * 4 + r];
    }
    const int c0 = 16 * w + lq * 4;
    #pragma unroll
    for (int n = 0; n < 4; ++n) {
      bf16x4 g4;
      #pragma unroll
      for (int r = 0; r < 4; ++r) {
        const float za = acc1[0][n][r] + ba[r];
        const float zb = acc1[1][n][r] + bs[r];
        const float th = 1.f - 2.f / (1.f + __expf(2.f * za));
        const float sg = 1.f / (1.f + __expf(-zb));
        g4[r] = f2b(th * sg);
      }
      const int tt = n * 16 + lh;
      *(bf16x4*)(ldsG + tt * GROWB + c0 * 2) = g4;
    }
  }
  __syncthreads();

  // ---- GEMM2: s[128 x TL] = Wout * G ----
  f32x4 acc2[4];
  #pragma unroll
  for (int n = 0; n < 4; ++n) acc2[n] = fz;
  const short* wol = wob + (size_t)layer * 128 * 128;
  #pragma unroll
  for (int ks = 0; ks < 4; ++ks) {
    const bf16x8 a = *(const bf16x8*)(wol + (16 * w + lh) * 128 + ks * 32 + lq * 8);
    #pragma unroll
    for (int n = 0; n < 4; ++n) {
      const int tt = n * 16 + lh;
      const bf16x8 bb = *(const bf16x8*)(ldsG + tt * GROWB + ks * 64 + lq * 16);
      acc2[n] = mfma16(a, bb, acc2[n]);
    }
  }

  // ---- epilogue ----
  {
    const size_t XOFFS = (size_t)NB * NC * NT;
    const int o0 = 16 * w + lq * 4;
    float bo[4];
    #pragma unroll
    for (int r = 0; r < 4; ++r) bo[r] = b_out[layer * 128 + o0 + r];
    #pragma unroll
    for (int n = 0; n < 4; ++n) {
      const int tg = t0 + n * 16 + lh;
      f32x4 s4;
      #pragma unroll
      for (int r = 0; r < 4; ++r) s4[r] = acc2[n][r] + bo[r];
      #pragma unroll
      for (int r = 0; r < 4; ++r)
        out[XOFFS + ((size_t)((layer * NB + b) * NC + o0 + r)) * NT + tg] = s4[r];
      const size_t xi = ((size_t)(b * NT + tg)) * NC + o0;
      const f32x4 h = *(const f32x4*)(xin + xi);
      f32x4 xn;
      #pragma unroll
      for (int r = 0; r < 4; ++r) xn[r] = s4[r] + h[r];
      *(f32x4*)(xout + xi) = xn;
      bf16x4 xb;
      #pragma unroll
      for (int r = 0; r < 4; ++r) xb[r] = f2b(xn[r]);
      const size_t rowB = ((size_t)(b * NT + tg)) * 256;
      const int ci = (o0 >> 3) ^ (tg & 7);
      *(bf16x4*)((char*)xbout + rowB + ci * 16 + (o0 & 7) * 2) = xb;
      if (last) {
        #pragma unroll
        for (int r = 0; r < 4; ++r)
          out[((size_t)(b * NC + o0 + r)) * NT + tg] = xn[r];
      }
    }
  }
}

extern "C" void kernel_launch(void* const* d_in, const int* in_sizes, int n_in,
                              void* d_out, int out_size, void* d_ws, size_t ws_size,
                              hipStream_t stream) {
  const float* x      = (const float*)d_in[0];
  const float* w_conv = (const float*)d_in[1];
  const float* b_conv = (const float*)d_in[2];
  const float* w_out  = (const float*)d_in[3];
  const float* b_out  = (const float*)d_in[4];
  float* out = (float*)d_out;

  const size_t XTN = (size_t)NB * NT * NC;      // 4,194,304
  float* xt_a = (float*)d_ws;
  float* xt_b = xt_a + XTN;
  short* xb_a = (short*)(xt_b + XTN);
  short* xb_b = xb_a + XTN;
  short* wcb  = xb_b + XTN;
  short* wob  = wcb + CONVN;

  pack_weights<<<(CONVN + WOUTN + 255) / 256, 256, 0, stream>>>(w_conv, w_out, wcb, wob);
  transpose_in<<<dim3(NT / 64, NC / 64, NB), 256, 0, stream>>>(x, xt_a, xb_a);

  static const int dil[NLAYER] = {1, 2, 4, 8, 16, 32, 64, 128, 256, 512,
                                  1, 2, 4, 8, 16, 32, 64, 128, 256, 512};
  for (int i = 0; i < NLAYER; ++i) {
    const float* xi = (i & 1) ? xt_b : xt_a;
    float*       xo = (i & 1) ? xt_a : xt_b;
    const short* xbi = (i & 1) ? xb_b : xb_a;
    short*       xbo = (i & 1) ? xb_a : xb_b;
    wavenet_layer<<<dim3(NT / TL, NB), 512, 0, stream>>>(
        wcb, b_conv, wob, b_out, xi, xbi, xo, xbo, out, i, dil[i],
        (i == NLAYER - 1) ? 1 : 0);
  }
}